// Round 18
// baseline (289.569 us; speedup 1.0000x reference)
//
#include <hip/hip_runtime.h>
#include <stdint.h>
#include <stddef.h>

// Problem constants (fixed by the reference)
#define NN 50000    // num nodes
#define NE 800000   // num edges
#define NR 50       // num relations
#define FIN 768
#define HD 256
#define NC 9
#define CAP 64      // per-node edge bucket capacity (Poisson(16); P(d>64) ~ 1e-18)

typedef __bf16 bf16x8 __attribute__((ext_vector_type(8)));
typedef float f32x4 __attribute__((ext_vector_type(4)));
typedef unsigned short ushort_t;

// ---------------- Threefry-2x32-20 (JAX / Random123, partitionable) ----------------
__host__ __device__ static inline void tf2x32(uint32_t k0, uint32_t k1,
                                              uint32_t x0, uint32_t x1,
                                              uint32_t& o0, uint32_t& o1) {
  uint32_t ks2 = k0 ^ k1 ^ 0x1BD11BDAu;
  x0 += k0; x1 += k1;
#define TF_R(r) { x0 += x1; x1 = (x1 << r) | (x1 >> (32 - r)); x1 ^= x0; }
  TF_R(13) TF_R(15) TF_R(26) TF_R(6)
  x0 += k1;  x1 += ks2 + 1u;
  TF_R(17) TF_R(29) TF_R(16) TF_R(24)
  x0 += ks2; x1 += k0 + 2u;
  TF_R(13) TF_R(15) TF_R(26) TF_R(6)
  x0 += k0;  x1 += k1 + 3u;
  TF_R(17) TF_R(29) TF_R(16) TF_R(24)
  x0 += k1;  x1 += ks2 + 4u;
  TF_R(13) TF_R(15) TF_R(26) TF_R(6)
  x0 += ks2; x1 += k0 + 5u;
#undef TF_R
  o0 = x0; o1 = x1;
}

__device__ static inline float jax_unif(uint32_t ka, uint32_t kb, uint32_t i) {
  uint32_t o0, o1;
  tf2x32(ka, kb, 0u, i, o0, o1);
  uint32_t bits = o0 ^ o1;
  return __uint_as_float((bits >> 9) | 0x3f800000u) - 1.0f;
}

// dropout(p=0.4)+relu on value v at flat index i
__device__ static inline float drelu(float v, uint32_t ka, uint32_t kb, uint32_t i) {
  float r = (jax_unif(ka, kb, i) < 0.6f) ? (v * (1.0f / 0.6f)) : 0.0f;
  return fmaxf(r, 0.0f);
}

// f32 -> bf16 (round half up), packed pair / single
__device__ static inline uint32_t pk2(float lo, float hi) {
  uint32_t a = (__float_as_uint(lo) + 0x8000u) >> 16;
  uint32_t b = (__float_as_uint(hi) + 0x8000u) & 0xFFFF0000u;
  return a | b;
}
__device__ static inline ushort_t bf1(float v) {
  return (ushort_t)((__float_as_uint(v) + 0x8000u) >> 16);
}
__device__ static inline float ulo(uint32_t u) { return __uint_as_float(u << 16); }
__device__ static inline float uhi(uint32_t u) { return __uint_as_float(u & 0xFFFF0000u); }

// LDS 64B-row tile byte offset for (row r, 16B-segment s), XOR-swizzled (involution)
// This exact formula measured SQ_LDS_BANK_CONFLICT = 0 (R14/R16).
__device__ static inline int swz(int r, int s) {
  return r * 64 + ((s ^ ((r >> 1) & 3)) << 4);
}

#define GLDS16(gp, lp) __builtin_amdgcn_global_load_lds(                        \
    (const __attribute__((address_space(1))) void*)(gp),                        \
    (__attribute__((address_space(3))) void*)(lp), 16, 0, 0)

// ---------------- prep ----------------

// bucketed edge fill (cursor atomics only — no deg pass, no scan) + Bcat build
__global__ __launch_bounds__(256) void fillb_k(const int* __restrict__ ei,
                                               const int* __restrict__ et,
                                               const float* __restrict__ basis1,
                                               const float* __restrict__ root1,
                                               unsigned* __restrict__ cursor,
                                               uint2* __restrict__ epw,
                                               ushort_t* __restrict__ Bcat) {
  int gid = blockIdx.x * 256 + threadIdx.x;
  if (gid < NE) {
    int src = ei[gid];
    int dst = ei[NE + gid];
    int t = et[gid];
    unsigned pos = atomicAdd(&cursor[dst], 1u);
    if (pos < CAP)
      epw[(size_t)dst * CAP + pos] =
          make_uint2((uint32_t)src | ((uint32_t)t << 16), 0x3f800000u);
  }
  if (gid < 512 * FIN) {
    int n = gid / FIN, k = gid - n * FIN;
    float v = (n < HD) ? basis1[k * HD + n] : root1[k * HD + (n - HD)];
    Bcat[gid] = bf1(v);
  }
}

// per-(dst,t) mean norms: wave per node, single pass (d <= 64). Count for edge
// e = #{i in node's bucket : t_i == t_e} via wave-uniform L1-hot loads.
__global__ __launch_bounds__(256) void norm_k(const unsigned* __restrict__ cursor,
                                              uint2* __restrict__ epw) {
  int node = blockIdx.x * 4 + (threadIdx.x >> 6);
  int lane = threadIdx.x & 63;
  if (node >= NN) return;
  int d = (int)cursor[node];
  uint2* ep = epw + (size_t)node * CAP;
  uint32_t my = (lane < d) ? ep[lane].x : 0u;
  uint32_t mt = my >> 16;
  int c = 0;
  for (int i = 0; i < d; ++i) {
    uint32_t ti = ep[i].x >> 16;  // wave-uniform, L1-hot
    c += (ti == mt) ? 1 : 0;
  }
  if (lane < d) ep[lane].y = __float_as_uint(1.0f / (float)c);
}

// ---------------- fused layer-1 GEMM: hxb[M][512](bf16) = x(f32) @ [basis1|root1] ----------------
// A staged as f32 via glds into TWO 8KB regions (verified-zero-conflict E/O
// swizzle, R14); f32->bf16 cvt at fragment-load time. B bf16 via glds.
// COUNTED-VMCNT PIPELINE (T4), 3 buffers, stage-2-ahead. T3 ordering: STAGE is
// issued right AFTER the barrier, BEFORE compute — safe because the staged
// buffer (s+2)%3 = (s-1)%3 was last read in compute(s-1), and every wave
// passed barrier(s) only after finishing compute(s-1). T5: setprio around
// the MFMA cluster (counted-vmcnt gives the wave role-split setprio needs).
// 128x128 tile, BK=32, 4 waves, 4x4 frags. XCD-pinned block mapping.
__global__ __launch_bounds__(256) void mfma_gemm_k(const float* __restrict__ A,
                                                   const ushort_t* __restrict__ Bc,
                                                   ushort_t* __restrict__ C, int M) {
  __shared__ alignas(16) unsigned char ldsA[3][16384];  // [E 8K | O 8K] per buf
  __shared__ alignas(16) unsigned char ldsB[3][8192];
  const int K = FIN;
  const int NT = K / 32;  // 24 K-steps

  int id = blockIdx.x;
  int xcd = id & 7, sq = id >> 3;
  int bm128 = xcd + 8 * (sq >> 2);
  if (bm128 >= (M + 127) / 128) return;
  int bm = bm128 * 128;
  int bn = (sq & 3) * 128;

  int t = threadIdx.x;
  int lane = t & 63, w = t >> 6;
  int wm = w >> 1, wn = w & 1;
  int fr = lane & 15, fs = lane >> 4;

  f32x4 acc[4][4];
#pragma unroll
  for (int m = 0; m < 4; ++m)
#pragma unroll
    for (int n = 0; n < 4; ++n) acc[m][n] = (f32x4){0.f, 0.f, 0.f, 0.f};

  // fragment read offsets — verified zero-conflict geometry (R14)
  int aofE[4], aofO[4], boff[4];
#pragma unroll
  for (int m = 0; m < 4; ++m) {
    int r = wm * 64 + m * 16 + fr;
    aofE[m] = swz(r, fs);           // k [8fs, 8fs+4)   (even quad)
    aofO[m] = 8192 + swz(r, fs);    // k [8fs+4, 8fs+8) (odd quad)
  }
#pragma unroll
  for (int n = 0; n < 4; ++n) boff[n] = swz(wn * 64 + n * 16 + fr, fs);

  // staging: thread t -> row r0 = t>>2, phys slot t&3; logical quad l0 (swizzled)
  int r0 = t >> 2;
  int l0 = (t & 3) ^ ((r0 >> 1) & 3);
  const float* srcA0 = A + (size_t)min(bm + r0, M - 1) * K + 8 * l0;       // even
  const float* srcA1 = A + (size_t)min(bm + 64 + r0, M - 1) * K + 8 * l0;
  const ushort_t* srcB0 = Bc + (size_t)(bn + r0) * K + l0 * 8;             // 8 bf16
  const ushort_t* srcB1 = Bc + (size_t)(bn + 64 + r0) * K + l0 * 8;

  // 6 glds per stage (4 A + 2 B); vmcnt counts these per-thread, in order.
#define STAGE(bi, k0) {                                                        \
    GLDS16(srcA0 + (k0),     ldsA[bi] + w * 1024);            /* E rows 0-63 */\
    GLDS16(srcA1 + (k0),     ldsA[bi] + 4096 + w * 1024);     /* E rows 64+  */\
    GLDS16(srcA0 + (k0) + 4, ldsA[bi] + 8192 + w * 1024);     /* O rows 0-63 */\
    GLDS16(srcA1 + (k0) + 4, ldsA[bi] + 12288 + w * 1024);    /* O rows 64+  */\
    GLDS16(srcB0 + (k0),     ldsB[bi] + w * 1024);                             \
    GLDS16(srcB1 + (k0),     ldsB[bi] + 4096 + w * 1024); }

  // prologue: two stages in flight (12 outstanding loads per thread)
  STAGE(0, 0);
  STAGE(1, 32);

  int cur = 0;
  for (int s = 0; s < NT; ++s) {
    // wait ONLY for the oldest stage (buf[cur]); newest stays in flight.
    if (s < NT - 1) {
      asm volatile("s_waitcnt vmcnt(6)" ::: "memory");
    } else {
      asm volatile("s_waitcnt vmcnt(0)" ::: "memory");
    }
    __builtin_amdgcn_sched_barrier(0);
    __builtin_amdgcn_s_barrier();   // all waves did their vmcnt -> buf[cur] ready
    // T3 ordering: issue next-next stage FIRST (one compute phase earlier).
    // buf[(s+2)%3] = buf[(s-1)%3]: last read in compute(s-1); all waves are
    // past barrier(s) -> finished compute(s-1) -> safe to overwrite.
    if (s + 2 < NT) {
      int nb = cur + 2; if (nb >= 3) nb -= 3;
      STAGE(nb, (s + 2) * 32);
    }
    bf16x8 af[4], bfr[4];
#pragma unroll
    for (int m = 0; m < 4; ++m) {
      f32x4 e4 = *(const f32x4*)(ldsA[cur] + aofE[m]);
      f32x4 o4 = *(const f32x4*)(ldsA[cur] + aofO[m]);
      uint4 au;
      au.x = pk2(e4[0], e4[1]); au.y = pk2(e4[2], e4[3]);
      au.z = pk2(o4[0], o4[1]); au.w = pk2(o4[2], o4[3]);
      af[m] = *(bf16x8*)&au;
    }
#pragma unroll
    for (int n = 0; n < 4; ++n) bfr[n] = *(const bf16x8*)(ldsB[cur] + boff[n]);
    __builtin_amdgcn_s_setprio(1);
#pragma unroll
    for (int m = 0; m < 4; ++m)
#pragma unroll
      for (int n = 0; n < 4; ++n)
        acc[m][n] = __builtin_amdgcn_mfma_f32_16x16x32_bf16(af[m], bfr[n],
                                                            acc[m][n], 0, 0, 0);
    __builtin_amdgcn_s_setprio(0);
    ++cur; if (cur == 3) cur = 0;
  }
#undef STAGE

  // epilogue: C/D layout col = lane&15, row = (lane>>4)*4 + reg  [m89-verified]
#pragma unroll
  for (int m = 0; m < 4; ++m) {
    int rbase = bm + wm * 64 + m * 16 + fs * 4;
#pragma unroll
    for (int r4 = 0; r4 < 4; ++r4) {
      int row = rbase + r4;
      if (row < M) {
        ushort_t* crow = C + (size_t)row * 512 + bn + wn * 64 + fr;
#pragma unroll
        for (int n = 0; n < 4; ++n) crow[n * 16] = bf1(acc[m][n][r4]);
      }
    }
  }
}

// ---------------- aggregation / epilogues ----------------

// one wave per dst node over hxb[NN][512] bf16 (cols 0..255 = hx, 256..511 = xr);
// unroll-by-8: 8 independent row loads in flight. Writes h1 (bf16) over xr half.
__global__ __launch_bounds__(256) void gather1_k(const unsigned* __restrict__ cursor,
                                                 const uint2* __restrict__ epw,
                                                 const float* __restrict__ comp1,
                                                 ushort_t* __restrict__ hxb,
                                                 const float* __restrict__ bias1,
                                                 uint32_t ka, uint32_t kb) {
  __shared__ float cs[NR];
  if (threadIdx.x < NR) cs[threadIdx.x] = comp1[threadIdx.x];
  __syncthreads();
  int node = blockIdx.x * 4 + (threadIdx.x >> 6);
  int lane = threadIdx.x & 63;
  if (node >= NN) return;
  int d = (int)cursor[node];
  const uint2* ep = epw + (size_t)node * CAP;
  float aA0 = 0.f, aA1 = 0.f, aA2 = 0.f, aA3 = 0.f;
  float aB0 = 0.f, aB1 = 0.f, aB2 = 0.f, aB3 = 0.f;
  int j = 0;
  for (; j + 8 <= d; j += 8) {
    uint2 e[8], u[8];
#pragma unroll
    for (int q = 0; q < 8; ++q) e[q] = ep[j + q];
#pragma unroll
    for (int q = 0; q < 8; ++q)
      u[q] = *(const uint2*)(hxb + (size_t)(e[q].x & 0xFFFFu) * 512 + lane * 4);
#pragma unroll
    for (int q = 0; q < 8; ++q) {
      float w_ = cs[e[q].x >> 16] * __uint_as_float(e[q].y);
      if (q & 1) {
        aB0 += w_ * ulo(u[q].x); aB1 += w_ * uhi(u[q].x);
        aB2 += w_ * ulo(u[q].y); aB3 += w_ * uhi(u[q].y);
      } else {
        aA0 += w_ * ulo(u[q].x); aA1 += w_ * uhi(u[q].x);
        aA2 += w_ * ulo(u[q].y); aA3 += w_ * uhi(u[q].y);
      }
    }
  }
  for (; j < d; ++j) {
    uint2 e0 = ep[j];
    uint2 u0 = *(const uint2*)(hxb + (size_t)(e0.x & 0xFFFFu) * 512 + lane * 4);
    float w0 = cs[e0.x >> 16] * __uint_as_float(e0.y);
    aA0 += w0 * ulo(u0.x); aA1 += w0 * uhi(u0.x);
    aA2 += w0 * ulo(u0.y); aA3 += w0 * uhi(u0.y);
  }
  float s0 = aA0 + aB0, s1 = aA1 + aB1, s2 = aA2 + aB2, s3 = aA3 + aB3;
  ushort_t* xrow = hxb + (size_t)node * 512 + 256 + lane * 4;
  uint2 xu = *(const uint2*)xrow;
  float4 b = *(const float4*)(bias1 + lane * 4);
  uint32_t base = (uint32_t)(node * HD + lane * 4);
  float ox = drelu(s0 + ulo(xu.x) + b.x, ka, kb, base + 0);
  float oy = drelu(s1 + uhi(xu.x) + b.y, ka, kb, base + 1);
  float oz = drelu(s2 + ulo(xu.y) + b.z, ka, kb, base + 2);
  float ow = drelu(s3 + uhi(xu.y) + b.w, ka, kb, base + 3);
  *(uint2*)xrow = make_uint2(pk2(ox, oy), pk2(oz, ow));
}

// layer-2 projections, thread per node: hxr2[n][0..8] = h1@basis2 ; [10..18] = h1@root2
// W reads are wave-uniform (broadcast, conflict-free). hxr2 row stride 20 floats.
__global__ __launch_bounds__(256) void gemm2_k(const ushort_t* __restrict__ hxb,
                                               const float* __restrict__ basis2,
                                               const float* __restrict__ root2,
                                               float* __restrict__ hxr2) {
  __shared__ float W[256][20];  // padded stride
  int tid = threadIdx.x;
  for (int p = tid; p < 256 * 18; p += 256) {
    int k = p / 18, c = p % 18;
    W[k][c] = (c < 9) ? basis2[k * 9 + c] : root2[k * 9 + (c - 9)];
  }
  __syncthreads();
  int n = blockIdx.x * 256 + tid;
  if (n >= NN) return;
  const ushort_t* hp = hxb + (size_t)n * 512 + 256;
  float acc[18];
#pragma unroll
  for (int c = 0; c < 18; ++c) acc[c] = 0.f;
  for (int k0 = 0; k0 < 256; k0 += 8) {
    uint4 u = *(const uint4*)(hp + k0);
    float f[8];
    f[0] = ulo(u.x); f[1] = uhi(u.x); f[2] = ulo(u.y); f[3] = uhi(u.y);
    f[4] = ulo(u.z); f[5] = uhi(u.z); f[6] = ulo(u.w); f[7] = uhi(u.w);
#pragma unroll
    for (int q = 0; q < 8; ++q)
#pragma unroll
      for (int c = 0; c < 18; ++c) acc[c] += f[q] * W[k0 + q][c];
  }
  float* op = hxr2 + (size_t)n * 20;
#pragma unroll
  for (int c = 0; c < 9; ++c) op[c] = acc[c];
#pragma unroll
  for (int c = 0; c < 9; ++c) op[10 + c] = acc[9 + c];
}

// one thread per dst node, unroll-by-4: out = relu(dropout(agg + xr2 + b2))
__global__ __launch_bounds__(256) void gather2_k(const unsigned* __restrict__ cursor,
                                                 const uint2* __restrict__ epw,
                                                 const float* __restrict__ comp2,
                                                 const float* __restrict__ hxr2,
                                                 const float* __restrict__ bias2,
                                                 float* __restrict__ out,
                                                 uint32_t ka, uint32_t kb) {
  __shared__ float cs[NR];
  if (threadIdx.x < NR) cs[threadIdx.x] = comp2[threadIdx.x];
  __syncthreads();
  int n = blockIdx.x * 256 + threadIdx.x;
  if (n >= NN) return;
  int d = (int)cursor[n];
  const uint2* ep = epw + (size_t)n * CAP;
  float a[9];
#pragma unroll
  for (int c = 0; c < 9; ++c) a[c] = 0.f;
  int j = 0;
  for (; j + 4 <= d; j += 4) {
    uint2 e[4];
    float4 pa[4], pb[4];
    float pe[4];
#pragma unroll
    for (int q = 0; q < 4; ++q) e[q] = ep[j + q];
#pragma unroll
    for (int q = 0; q < 4; ++q) {
      const float* hp = hxr2 + (size_t)(e[q].x & 0xFFFFu) * 20;
      pa[q] = *(const float4*)hp;
      pb[q] = *(const float4*)(hp + 4);
      pe[q] = hp[8];
    }
#pragma unroll
    for (int q = 0; q < 4; ++q) {
      float w_ = cs[e[q].x >> 16] * __uint_as_float(e[q].y);
      a[0] += w_ * pa[q].x; a[1] += w_ * pa[q].y;
      a[2] += w_ * pa[q].z; a[3] += w_ * pa[q].w;
      a[4] += w_ * pb[q].x; a[5] += w_ * pb[q].y;
      a[6] += w_ * pb[q].z; a[7] += w_ * pb[q].w;
      a[8] += w_ * pe[q];
    }
  }
  for (; j < d; ++j) {
    uint2 e0 = ep[j];
    const float* hp = hxr2 + (size_t)(e0.x & 0xFFFFu) * 20;
    float4 p0a = *(const float4*)hp, p0b = *(const float4*)(hp + 4);
    float p0e = hp[8];
    float w0 = cs[e0.x >> 16] * __uint_as_float(e0.y);
    a[0] += w0 * p0a.x; a[1] += w0 * p0a.y; a[2] += w0 * p0a.z; a[3] += w0 * p0a.w;
    a[4] += w0 * p0b.x; a[5] += w0 * p0b.y; a[6] += w0 * p0b.z; a[7] += w0 * p0b.w;
    a[8] += w0 * p0e;
  }
  const float* xp = hxr2 + (size_t)n * 20 + 10;
#pragma unroll
  for (int c = 0; c < 9; ++c) {
    float v = a[c] + xp[c] + bias2[c];
    out[n * 9 + c] = drelu(v, ka, kb, (uint32_t)(n * 9 + c));
  }
}

// ---------------- launch ----------------
extern "C" void kernel_launch(void* const* d_in, const int* in_sizes, int n_in,
                              void* d_out, int out_size, void* d_ws, size_t ws_size,
                              hipStream_t stream) {
  (void)in_sizes; (void)n_in; (void)out_size; (void)ws_size;
  const float* x      = (const float*)d_in[0];
  const int*   ei     = (const int*)d_in[1];
  const int*   et     = (const int*)d_in[2];
  const float* basis1 = (const float*)d_in[4];
  const float* comp1  = (const float*)d_in[5];
  const float* root1  = (const float*)d_in[6];
  const float* bias1  = (const float*)d_in[7];
  const float* basis2 = (const float*)d_in[8];
  const float* comp2  = (const float*)d_in[9];
  const float* root2  = (const float*)d_in[10];
  const float* bias2  = (const float*)d_in[11];
  float* out = (float*)d_out;

  // workspace layout (bytes); total ~81.8 MB (no xb — GEMM reads x directly)
  char* ws = (char*)d_ws;
  ushort_t* Bcat   = (ushort_t*)(ws);                        //     786,432
  uint2* epw       = (uint2*)(ws + 786432);                  //  25,600,000
  unsigned* cursor = (unsigned*)(ws + 26386432);             //     200,128
  ushort_t* hxb    = (ushort_t*)(ws + 26586560);             //  51,200,000
  float* hxr2      = (float*)(ws + 77786560);                //   4,000,128

  // k1, k2 = jax.random.split(jax.random.key(42)), partitionable scheme
  uint32_t k1a, k1b, k2a, k2b;
  tf2x32(0u, 42u, 0u, 0u, k1a, k1b);
  tf2x32(0u, 42u, 0u, 1u, k2a, k2b);

  hipMemsetAsync(cursor, 0, 200128, stream);

  fillb_k<<<(NE + 255) / 256, 256, 0, stream>>>(ei, et, basis1, root1, cursor,
                                                epw, Bcat);
  norm_k<<<(NN + 3) / 4, 256, 0, stream>>>(cursor, epw);

  // 1568 = 8 XCDs x 196 seq slots; 4 blocks idle (bm128 guard)
  mfma_gemm_k<<<1568, 256, 0, stream>>>(x, Bcat, hxb, NN);

  gather1_k<<<(NN + 3) / 4, 256, 0, stream>>>(cursor, epw, comp1, hxb, bias1,
                                              k1a, k1b);

  gemm2_k<<<(NN + 255) / 256, 256, 0, stream>>>(hxb, basis2, root2, hxr2);

  gather2_k<<<(NN + 255) / 256, 256, 0, stream>>>(cursor, epw, comp2, hxr2,
                                                  bias2, out, k2a, k2b);
}

// Round 19
// 247.210 us; speedup vs baseline: 1.1713x; 1.1713x over previous
//
#include <hip/hip_runtime.h>
#include <stdint.h>
#include <stddef.h>

// Problem constants (fixed by the reference)
#define NN 50000    // num nodes
#define NE 800000   // num edges
#define NR 50       // num relations
#define FIN 768
#define HD 256
#define NC 9
#define CAP 64      // per-node edge bucket capacity (max degree <= 64, verified:
                    // rounds 11-18 passed with this cap and exact absmax)

typedef __bf16 bf16x8 __attribute__((ext_vector_type(8)));
typedef float f32x4 __attribute__((ext_vector_type(4)));
typedef unsigned short ushort_t;

// ---------------- Threefry-2x32-20 (JAX / Random123, partitionable) ----------------
__host__ __device__ static inline void tf2x32(uint32_t k0, uint32_t k1,
                                              uint32_t x0, uint32_t x1,
                                              uint32_t& o0, uint32_t& o1) {
  uint32_t ks2 = k0 ^ k1 ^ 0x1BD11BDAu;
  x0 += k0; x1 += k1;
#define TF_R(r) { x0 += x1; x1 = (x1 << r) | (x1 >> (32 - r)); x1 ^= x0; }
  TF_R(13) TF_R(15) TF_R(26) TF_R(6)
  x0 += k1;  x1 += ks2 + 1u;
  TF_R(17) TF_R(29) TF_R(16) TF_R(24)
  x0 += ks2; x1 += k0 + 2u;
  TF_R(13) TF_R(15) TF_R(26) TF_R(6)
  x0 += k0;  x1 += k1 + 3u;
  TF_R(17) TF_R(29) TF_R(16) TF_R(24)
  x0 += k1;  x1 += ks2 + 4u;
  TF_R(13) TF_R(15) TF_R(26) TF_R(6)
  x0 += ks2; x1 += k0 + 5u;
#undef TF_R
  o0 = x0; o1 = x1;
}

__device__ static inline float jax_unif(uint32_t ka, uint32_t kb, uint32_t i) {
  uint32_t o0, o1;
  tf2x32(ka, kb, 0u, i, o0, o1);
  uint32_t bits = o0 ^ o1;
  return __uint_as_float((bits >> 9) | 0x3f800000u) - 1.0f;
}

// dropout(p=0.4)+relu on value v at flat index i
__device__ static inline float drelu(float v, uint32_t ka, uint32_t kb, uint32_t i) {
  float r = (jax_unif(ka, kb, i) < 0.6f) ? (v * (1.0f / 0.6f)) : 0.0f;
  return fmaxf(r, 0.0f);
}

// f32 -> bf16 (round half up), packed pair / single
__device__ static inline uint32_t pk2(float lo, float hi) {
  uint32_t a = (__float_as_uint(lo) + 0x8000u) >> 16;
  uint32_t b = (__float_as_uint(hi) + 0x8000u) & 0xFFFF0000u;
  return a | b;
}
__device__ static inline ushort_t bf1(float v) {
  return (ushort_t)((__float_as_uint(v) + 0x8000u) >> 16);
}
__device__ static inline float ulo(uint32_t u) { return __uint_as_float(u << 16); }
__device__ static inline float uhi(uint32_t u) { return __uint_as_float(u & 0xFFFF0000u); }

// LDS 64B-row tile byte offset for (row r, 16B-segment s), XOR-swizzled (involution)
// This exact formula measured SQ_LDS_BANK_CONFLICT = 0 (R14/R16).
__device__ static inline int swz(int r, int s) {
  return r * 64 + ((s ^ ((r >> 1) & 3)) << 4);
}

#define GLDS16(gp, lp) __builtin_amdgcn_global_load_lds(                        \
    (const __attribute__((address_space(1))) void*)(gp),                        \
    (__attribute__((address_space(3))) void*)(lp), 16, 0, 0)

// ---------------- prep ----------------

// Bcat build only (fill folded into the GEMM preamble)
__global__ __launch_bounds__(256) void bcat_k(const float* __restrict__ basis1,
                                              const float* __restrict__ root1,
                                              ushort_t* __restrict__ Bcat) {
  int gid = blockIdx.x * 256 + threadIdx.x;
  if (gid < 512 * FIN) {
    int n = gid / FIN, k = gid - n * FIN;
    float v = (n < HD) ? basis1[k * HD + n] : root1[k * HD + (n - HD)];
    Bcat[gid] = bf1(v);
  }
}

// ---------------- fused layer-1 GEMM: hxb[M][512](bf16) = x(f32) @ [basis1|root1] ----------------
// PREAMBLE: each block fills a ~511-edge slice of the buckets (atomics overlap
// with the pipeline's latency slots; vmcnt drained before the prologue so the
// counted-vmcnt discipline is untouched). Replaces the serial fillb_k.
// MAIN: R16-verbatim counted-vmcnt pipeline (T4): 3 LDS buffers, stage-2-ahead,
// per step s_waitcnt vmcnt(6) + s_barrier; STAGE after compute; no setprio
// (R18 showed hoist/setprio regress in this structure). A staged f32 via glds
// into E/O 8KB regions (zero-conflict swizzle), cvt at fragment-load; B bf16.
// 128x128 tile, BK=32, 4 waves, 4x4 frags. XCD-pinned block mapping.
__global__ __launch_bounds__(256) void mfma_gemm_k(const float* __restrict__ A,
                                                   const ushort_t* __restrict__ Bc,
                                                   ushort_t* __restrict__ C, int M,
                                                   const int* __restrict__ ei,
                                                   const int* __restrict__ et,
                                                   unsigned* __restrict__ cursor,
                                                   uint2* __restrict__ epw) {
  __shared__ alignas(16) unsigned char ldsA[3][16384];  // [E 8K | O 8K] per buf
  __shared__ alignas(16) unsigned char ldsB[3][8192];
  const int K = FIN;
  const int NT = K / 32;  // 24 K-steps

  int t = threadIdx.x;

  // ---- edge-fill preamble (all blocks, incl. the 4 guard-idle ones) ----
  {
    const int EPB = (NE + 1567) / 1568;  // 511 edges/block
    int e0 = blockIdx.x * EPB;
    int e1 = min(e0 + EPB, NE);
    for (int e = e0 + t; e < e1; e += 256) {
      int src = ei[e];
      int dst = ei[NE + e];
      int ty = et[e];
      unsigned pos = atomicAdd(&cursor[dst], 1u);
      if (pos < CAP)
        epw[(size_t)dst * CAP + pos] =
            make_uint2((uint32_t)src | ((uint32_t)ty << 16), 0u);
    }
  }

  int id = blockIdx.x;
  int xcd = id & 7, sq = id >> 3;
  int bm128 = xcd + 8 * (sq >> 2);
  if (bm128 >= (M + 127) / 128) return;
  int bm = bm128 * 128;
  int bn = (sq & 3) * 128;

  int lane = t & 63, w = t >> 6;
  int wm = w >> 1, wn = w & 1;
  int fr = lane & 15, fs = lane >> 4;

  f32x4 acc[4][4];
#pragma unroll
  for (int m = 0; m < 4; ++m)
#pragma unroll
    for (int n = 0; n < 4; ++n) acc[m][n] = (f32x4){0.f, 0.f, 0.f, 0.f};

  // fragment read offsets — verified zero-conflict geometry (R14)
  int aofE[4], aofO[4], boff[4];
#pragma unroll
  for (int m = 0; m < 4; ++m) {
    int r = wm * 64 + m * 16 + fr;
    aofE[m] = swz(r, fs);           // k [8fs, 8fs+4)   (even quad)
    aofO[m] = 8192 + swz(r, fs);    // k [8fs+4, 8fs+8) (odd quad)
  }
#pragma unroll
  for (int n = 0; n < 4; ++n) boff[n] = swz(wn * 64 + n * 16 + fr, fs);

  // staging: thread t -> row r0 = t>>2, phys slot t&3; logical quad l0 (swizzled)
  int r0 = t >> 2;
  int l0 = (t & 3) ^ ((r0 >> 1) & 3);
  const float* srcA0 = A + (size_t)min(bm + r0, M - 1) * K + 8 * l0;       // even
  const float* srcA1 = A + (size_t)min(bm + 64 + r0, M - 1) * K + 8 * l0;
  const ushort_t* srcB0 = Bc + (size_t)(bn + r0) * K + l0 * 8;             // 8 bf16
  const ushort_t* srcB1 = Bc + (size_t)(bn + 64 + r0) * K + l0 * 8;

  // 6 glds per stage (4 A + 2 B); vmcnt counts these per-thread, in order.
#define STAGE(bi, k0) {                                                        \
    GLDS16(srcA0 + (k0),     ldsA[bi] + w * 1024);            /* E rows 0-63 */\
    GLDS16(srcA1 + (k0),     ldsA[bi] + 4096 + w * 1024);     /* E rows 64+  */\
    GLDS16(srcA0 + (k0) + 4, ldsA[bi] + 8192 + w * 1024);     /* O rows 0-63 */\
    GLDS16(srcA1 + (k0) + 4, ldsA[bi] + 12288 + w * 1024);    /* O rows 64+  */\
    GLDS16(srcB0 + (k0),     ldsB[bi] + w * 1024);                             \
    GLDS16(srcB1 + (k0),     ldsB[bi] + 4096 + w * 1024); }

  // drain preamble memory ops so vmcnt accounting starts at 0
  asm volatile("s_waitcnt vmcnt(0)" ::: "memory");
  __builtin_amdgcn_sched_barrier(0);

  // prologue: two stages in flight (12 outstanding loads per thread)
  STAGE(0, 0);
  STAGE(1, 32);

  int cur = 0;
  for (int s = 0; s < NT; ++s) {
    // wait ONLY for the oldest stage (buf[cur]); newest stays in flight.
    if (s < NT - 1) {
      asm volatile("s_waitcnt vmcnt(6)" ::: "memory");
    } else {
      asm volatile("s_waitcnt vmcnt(0)" ::: "memory");
    }
    __builtin_amdgcn_sched_barrier(0);
    __builtin_amdgcn_s_barrier();   // all waves did their vmcnt -> buf[cur] ready
    bf16x8 af[4], bfr[4];
#pragma unroll
    for (int m = 0; m < 4; ++m) {
      f32x4 e4 = *(const f32x4*)(ldsA[cur] + aofE[m]);
      f32x4 o4 = *(const f32x4*)(ldsA[cur] + aofO[m]);
      uint4 au;
      au.x = pk2(e4[0], e4[1]); au.y = pk2(e4[2], e4[3]);
      au.z = pk2(o4[0], o4[1]); au.w = pk2(o4[2], o4[3]);
      af[m] = *(bf16x8*)&au;
    }
#pragma unroll
    for (int n = 0; n < 4; ++n) bfr[n] = *(const bf16x8*)(ldsB[cur] + boff[n]);
#pragma unroll
    for (int m = 0; m < 4; ++m)
#pragma unroll
      for (int n = 0; n < 4; ++n)
        acc[m][n] = __builtin_amdgcn_mfma_f32_16x16x32_bf16(af[m], bfr[n],
                                                            acc[m][n], 0, 0, 0);
    // stage buf[(s+2)%3] = buf[(s-1)%3]: last read in step s-1, which every
    // wave finished before barrier(s) -> safe to overwrite.
    if (s + 2 < NT) {
      int nb = cur + 2; if (nb >= 3) nb -= 3;
      STAGE(nb, (s + 2) * 32);
    }
    ++cur; if (cur == 3) cur = 0;
  }
#undef STAGE

  // epilogue: C/D layout col = lane&15, row = (lane>>4)*4 + reg  [m89-verified]
#pragma unroll
  for (int m = 0; m < 4; ++m) {
    int rbase = bm + wm * 64 + m * 16 + fs * 4;
#pragma unroll
    for (int r4 = 0; r4 < 4; ++r4) {
      int row = rbase + r4;
      if (row < M) {
        ushort_t* crow = C + (size_t)row * 512 + bn + wn * 64 + fr;
#pragma unroll
        for (int n = 0; n < 4; ++n) crow[n * 16] = bf1(acc[m][n][r4]);
      }
    }
  }
}

// ---------------- aggregation / epilogues ----------------

// one wave per dst node over hxb[NN][512] bf16 (cols 0..255 = hx, 256..511 = xr);
// INLINE NORM (replaces norm_k): lane l owns edge l, computes its (dst,t) count
// in one d-iteration wave-uniform loop, broadcasts ic via shfl in the main
// loop, and writes ep[l].y = ic for gather2. unroll-by-8 gather main loop.
// Writes h1 (bf16) over own row's xr half.
__global__ __launch_bounds__(256) void gather1_k(const unsigned* __restrict__ cursor,
                                                 uint2* __restrict__ epw,
                                                 const float* __restrict__ comp1,
                                                 ushort_t* __restrict__ hxb,
                                                 const float* __restrict__ bias1,
                                                 uint32_t ka, uint32_t kb) {
  __shared__ float cs[NR];
  if (threadIdx.x < NR) cs[threadIdx.x] = comp1[threadIdx.x];
  __syncthreads();
  int node = blockIdx.x * 4 + (threadIdx.x >> 6);
  int lane = threadIdx.x & 63;
  if (node >= NN) return;
  int d = min((int)cursor[node], CAP);
  uint2* ep = epw + (size_t)node * CAP;
  // inline per-(dst,t) mean norm
  uint32_t myx = (lane < d) ? ep[lane].x : 0u;
  uint32_t mt = myx >> 16;
  int c = 0;
  for (int i = 0; i < d; ++i) c += ((ep[i].x >> 16) == mt) ? 1 : 0;
  float ic = 1.0f / (float)c;
  if (lane < d) ep[lane].y = __float_as_uint(ic);  // consumed by gather2
  float aA0 = 0.f, aA1 = 0.f, aA2 = 0.f, aA3 = 0.f;
  float aB0 = 0.f, aB1 = 0.f, aB2 = 0.f, aB3 = 0.f;
  int j = 0;
  for (; j + 8 <= d; j += 8) {
    uint32_t ex[8];
    uint2 u[8];
#pragma unroll
    for (int q = 0; q < 8; ++q) ex[q] = ep[j + q].x;
#pragma unroll
    for (int q = 0; q < 8; ++q)
      u[q] = *(const uint2*)(hxb + (size_t)(ex[q] & 0xFFFFu) * 512 + lane * 4);
#pragma unroll
    for (int q = 0; q < 8; ++q) {
      float w_ = cs[ex[q] >> 16] * __shfl(ic, j + q, 64);
      if (q & 1) {
        aB0 += w_ * ulo(u[q].x); aB1 += w_ * uhi(u[q].x);
        aB2 += w_ * ulo(u[q].y); aB3 += w_ * uhi(u[q].y);
      } else {
        aA0 += w_ * ulo(u[q].x); aA1 += w_ * uhi(u[q].x);
        aA2 += w_ * ulo(u[q].y); aA3 += w_ * uhi(u[q].y);
      }
    }
  }
  for (; j < d; ++j) {
    uint32_t ex = ep[j].x;
    uint2 u0 = *(const uint2*)(hxb + (size_t)(ex & 0xFFFFu) * 512 + lane * 4);
    float w0 = cs[ex >> 16] * __shfl(ic, j, 64);
    aA0 += w0 * ulo(u0.x); aA1 += w0 * uhi(u0.x);
    aA2 += w0 * ulo(u0.y); aA3 += w0 * uhi(u0.y);
  }
  float s0 = aA0 + aB0, s1 = aA1 + aB1, s2 = aA2 + aB2, s3 = aA3 + aB3;
  ushort_t* xrow = hxb + (size_t)node * 512 + 256 + lane * 4;
  uint2 xu = *(const uint2*)xrow;
  float4 b = *(const float4*)(bias1 + lane * 4);
  uint32_t base = (uint32_t)(node * HD + lane * 4);
  float ox = drelu(s0 + ulo(xu.x) + b.x, ka, kb, base + 0);
  float oy = drelu(s1 + uhi(xu.x) + b.y, ka, kb, base + 1);
  float oz = drelu(s2 + ulo(xu.y) + b.z, ka, kb, base + 2);
  float ow = drelu(s3 + uhi(xu.y) + b.w, ka, kb, base + 3);
  *(uint2*)xrow = make_uint2(pk2(ox, oy), pk2(oz, ow));
}

// layer-2 projections, thread per node: hxr2[n][0..8] = h1@basis2 ; [10..18] = h1@root2
// W reads are wave-uniform (broadcast, conflict-free). hxr2 row stride 20 floats.
__global__ __launch_bounds__(256) void gemm2_k(const ushort_t* __restrict__ hxb,
                                               const float* __restrict__ basis2,
                                               const float* __restrict__ root2,
                                               float* __restrict__ hxr2) {
  __shared__ float W[256][20];  // padded stride
  int tid = threadIdx.x;
  for (int p = tid; p < 256 * 18; p += 256) {
    int k = p / 18, c = p % 18;
    W[k][c] = (c < 9) ? basis2[k * 9 + c] : root2[k * 9 + (c - 9)];
  }
  __syncthreads();
  int n = blockIdx.x * 256 + tid;
  if (n >= NN) return;
  const ushort_t* hp = hxb + (size_t)n * 512 + 256;
  float acc[18];
#pragma unroll
  for (int c = 0; c < 18; ++c) acc[c] = 0.f;
  for (int k0 = 0; k0 < 256; k0 += 8) {
    uint4 u = *(const uint4*)(hp + k0);
    float f[8];
    f[0] = ulo(u.x); f[1] = uhi(u.x); f[2] = ulo(u.y); f[3] = uhi(u.y);
    f[4] = ulo(u.z); f[5] = uhi(u.z); f[6] = ulo(u.w); f[7] = uhi(u.w);
#pragma unroll
    for (int q = 0; q < 8; ++q)
#pragma unroll
      for (int c = 0; c < 18; ++c) acc[c] += f[q] * W[k0 + q][c];
  }
  float* op = hxr2 + (size_t)n * 20;
#pragma unroll
  for (int c = 0; c < 9; ++c) op[c] = acc[c];
#pragma unroll
  for (int c = 0; c < 9; ++c) op[10 + c] = acc[9 + c];
}

// one thread per dst node, unroll-by-4: out = relu(dropout(agg + xr2 + b2))
__global__ __launch_bounds__(256) void gather2_k(const unsigned* __restrict__ cursor,
                                                 const uint2* __restrict__ epw,
                                                 const float* __restrict__ comp2,
                                                 const float* __restrict__ hxr2,
                                                 const float* __restrict__ bias2,
                                                 float* __restrict__ out,
                                                 uint32_t ka, uint32_t kb) {
  __shared__ float cs[NR];
  if (threadIdx.x < NR) cs[threadIdx.x] = comp2[threadIdx.x];
  __syncthreads();
  int n = blockIdx.x * 256 + threadIdx.x;
  if (n >= NN) return;
  int d = min((int)cursor[n], CAP);
  const uint2* ep = epw + (size_t)n * CAP;
  float a[9];
#pragma unroll
  for (int c = 0; c < 9; ++c) a[c] = 0.f;
  int j = 0;
  for (; j + 4 <= d; j += 4) {
    uint2 e[4];
    float4 pa[4], pb[4];
    float pe[4];
#pragma unroll
    for (int q = 0; q < 4; ++q) e[q] = ep[j + q];
#pragma unroll
    for (int q = 0; q < 4; ++q) {
      const float* hp = hxr2 + (size_t)(e[q].x & 0xFFFFu) * 20;
      pa[q] = *(const float4*)hp;
      pb[q] = *(const float4*)(hp + 4);
      pe[q] = hp[8];
    }
#pragma unroll
    for (int q = 0; q < 4; ++q) {
      float w_ = cs[e[q].x >> 16] * __uint_as_float(e[q].y);
      a[0] += w_ * pa[q].x; a[1] += w_ * pa[q].y;
      a[2] += w_ * pa[q].z; a[3] += w_ * pa[q].w;
      a[4] += w_ * pb[q].x; a[5] += w_ * pb[q].y;
      a[6] += w_ * pb[q].z; a[7] += w_ * pb[q].w;
      a[8] += w_ * pe[q];
    }
  }
  for (; j < d; ++j) {
    uint2 e0 = ep[j];
    const float* hp = hxr2 + (size_t)(e0.x & 0xFFFFu) * 20;
    float4 p0a = *(const float4*)hp, p0b = *(const float4*)(hp + 4);
    float p0e = hp[8];
    float w0 = cs[e0.x >> 16] * __uint_as_float(e0.y);
    a[0] += w0 * p0a.x; a[1] += w0 * p0a.y; a[2] += w0 * p0a.z; a[3] += w0 * p0a.w;
    a[4] += w0 * p0b.x; a[5] += w0 * p0b.y; a[6] += w0 * p0b.z; a[7] += w0 * p0b.w;
    a[8] += w0 * p0e;
  }
  const float* xp = hxr2 + (size_t)n * 20 + 10;
#pragma unroll
  for (int c = 0; c < 9; ++c) {
    float v = a[c] + xp[c] + bias2[c];
    out[n * 9 + c] = drelu(v, ka, kb, (uint32_t)(n * 9 + c));
  }
}

// ---------------- launch ----------------
extern "C" void kernel_launch(void* const* d_in, const int* in_sizes, int n_in,
                              void* d_out, int out_size, void* d_ws, size_t ws_size,
                              hipStream_t stream) {
  (void)in_sizes; (void)n_in; (void)out_size; (void)ws_size;
  const float* x      = (const float*)d_in[0];
  const int*   ei     = (const int*)d_in[1];
  const int*   et     = (const int*)d_in[2];
  const float* basis1 = (const float*)d_in[4];
  const float* comp1  = (const float*)d_in[5];
  const float* root1  = (const float*)d_in[6];
  const float* bias1  = (const float*)d_in[7];
  const float* basis2 = (const float*)d_in[8];
  const float* comp2  = (const float*)d_in[9];
  const float* root2  = (const float*)d_in[10];
  const float* bias2  = (const float*)d_in[11];
  float* out = (float*)d_out;

  // workspace layout (bytes); total ~81.8 MB (no xb — GEMM reads x directly)
  char* ws = (char*)d_ws;
  ushort_t* Bcat   = (ushort_t*)(ws);                        //     786,432
  uint2* epw       = (uint2*)(ws + 786432);                  //  25,600,000
  unsigned* cursor = (unsigned*)(ws + 26386432);             //     200,128
  ushort_t* hxb    = (ushort_t*)(ws + 26586560);             //  51,200,000
  float* hxr2      = (float*)(ws + 77786560);                //   4,000,128

  // k1, k2 = jax.random.split(jax.random.key(42)), partitionable scheme
  uint32_t k1a, k1b, k2a, k2b;
  tf2x32(0u, 42u, 0u, 0u, k1a, k1b);
  tf2x32(0u, 42u, 0u, 1u, k2a, k2b);

  hipMemsetAsync(cursor, 0, 200128, stream);

  bcat_k<<<(512 * FIN + 255) / 256, 256, 0, stream>>>(basis1, root1, Bcat);

  // 1568 = 8 XCDs x 196 seq slots; 4 blocks do only the edge-fill preamble
  mfma_gemm_k<<<1568, 256, 0, stream>>>(x, Bcat, hxb, NN, ei, et, cursor, epw);

  gather1_k<<<(NN + 3) / 4, 256, 0, stream>>>(cursor, epw, comp1, hxb, bias1,
                                              k1a, k1b);

  gemm2_k<<<(NN + 255) / 256, 256, 0, stream>>>(hxb, basis2, root2, hxr2);

  gather2_k<<<(NN + 255) / 256, 256, 0, stream>>>(cursor, epw, comp2, hxr2,
                                                  bias2, out, k2a, k2b);
}

// Round 20
// 242.993 us; speedup vs baseline: 1.1917x; 1.0174x over previous
//
#include <hip/hip_runtime.h>
#include <stdint.h>
#include <stddef.h>

// Problem constants (fixed by the reference)
#define NN 50000    // num nodes
#define NE 800000   // num edges
#define NR 50       // num relations
#define FIN 768
#define HD 256
#define NC 9
#define CAP 64      // per-node edge bucket capacity (max degree <= 64, verified
                    // rounds 11-19: passed with exact absmax)

typedef __bf16 bf16x8 __attribute__((ext_vector_type(8)));
typedef float f32x4 __attribute__((ext_vector_type(4)));
typedef unsigned short ushort_t;

// ---------------- Threefry-2x32-20 (JAX / Random123, partitionable) ----------------
__host__ __device__ static inline void tf2x32(uint32_t k0, uint32_t k1,
                                              uint32_t x0, uint32_t x1,
                                              uint32_t& o0, uint32_t& o1) {
  uint32_t ks2 = k0 ^ k1 ^ 0x1BD11BDAu;
  x0 += k0; x1 += k1;
#define TF_R(r) { x0 += x1; x1 = (x1 << r) | (x1 >> (32 - r)); x1 ^= x0; }
  TF_R(13) TF_R(15) TF_R(26) TF_R(6)
  x0 += k1;  x1 += ks2 + 1u;
  TF_R(17) TF_R(29) TF_R(16) TF_R(24)
  x0 += ks2; x1 += k0 + 2u;
  TF_R(13) TF_R(15) TF_R(26) TF_R(6)
  x0 += k0;  x1 += k1 + 3u;
  TF_R(17) TF_R(29) TF_R(16) TF_R(24)
  x0 += k1;  x1 += ks2 + 4u;
  TF_R(13) TF_R(15) TF_R(26) TF_R(6)
  x0 += ks2; x1 += k0 + 5u;
#undef TF_R
  o0 = x0; o1 = x1;
}

__device__ static inline float jax_unif(uint32_t ka, uint32_t kb, uint32_t i) {
  uint32_t o0, o1;
  tf2x32(ka, kb, 0u, i, o0, o1);
  uint32_t bits = o0 ^ o1;
  return __uint_as_float((bits >> 9) | 0x3f800000u) - 1.0f;
}

// dropout(p=0.4)+relu on value v at flat index i
__device__ static inline float drelu(float v, uint32_t ka, uint32_t kb, uint32_t i) {
  float r = (jax_unif(ka, kb, i) < 0.6f) ? (v * (1.0f / 0.6f)) : 0.0f;
  return fmaxf(r, 0.0f);
}

// f32 -> bf16 (round half up), packed pair / single
__device__ static inline uint32_t pk2(float lo, float hi) {
  uint32_t a = (__float_as_uint(lo) + 0x8000u) >> 16;
  uint32_t b = (__float_as_uint(hi) + 0x8000u) & 0xFFFF0000u;
  return a | b;
}
__device__ static inline ushort_t bf1(float v) {
  return (ushort_t)((__float_as_uint(v) + 0x8000u) >> 16);
}
__device__ static inline float ulo(uint32_t u) { return __uint_as_float(u << 16); }
__device__ static inline float uhi(uint32_t u) { return __uint_as_float(u & 0xFFFF0000u); }

// LDS 64B-row tile byte offset for (row r, 16B-segment s), XOR-swizzled (involution)
// This exact formula measured SQ_LDS_BANK_CONFLICT = 0 (R14/R16).
__device__ static inline int swz(int r, int s) {
  return r * 64 + ((s ^ ((r >> 1) & 3)) << 4);
}

#define GLDS16(gp, lp) __builtin_amdgcn_global_load_lds(                        \
    (const __attribute__((address_space(1))) void*)(gp),                        \
    (__attribute__((address_space(3))) void*)(lp), 16, 0, 0)

// ---------------- prep ----------------

// Bcat build only (edge-fill folded into the GEMM postamble)
__global__ __launch_bounds__(256) void bcat_k(const float* __restrict__ basis1,
                                              const float* __restrict__ root1,
                                              ushort_t* __restrict__ Bcat) {
  int gid = blockIdx.x * 256 + threadIdx.x;
  if (gid < 512 * FIN) {
    int n = gid / FIN, k = gid - n * FIN;
    float v = (n < HD) ? basis1[k * HD + n] : root1[k * HD + (n - HD)];
    Bcat[gid] = bf1(v);
  }
}

// ---------------- fused layer-1 GEMM: hxb[M][512](bf16) = x(f32) @ [basis1|root1] ----------------
// MAIN: R16 counted-vmcnt pipeline (T4): 3 LDS buffers, stage-2-ahead, per step
// s_waitcnt vmcnt(6) + s_barrier; STAGE after compute (R18: hoist/setprio hurt).
// A staged f32 via glds into E/O 8KB regions (zero-conflict swizzle), cvt at
// fragment-load; B bf16. 128x128 tile, BK=32, 4 waves. XCD-pinned mapping.
// POSTAMBLE: each block fills a ~511-edge slice of the buckets AFTER its
// C-write — no vmcnt drain before the pipeline, and fill latency overlaps
// co-resident / later blocks' compute. All fills done at kernel end.
__global__ __launch_bounds__(256) void mfma_gemm_k(const float* __restrict__ A,
                                                   const ushort_t* __restrict__ Bc,
                                                   ushort_t* __restrict__ C, int M,
                                                   const int* __restrict__ ei,
                                                   const int* __restrict__ et,
                                                   unsigned* __restrict__ cursor,
                                                   uint2* __restrict__ epw) {
  __shared__ alignas(16) unsigned char ldsA[3][16384];  // [E 8K | O 8K] per buf
  __shared__ alignas(16) unsigned char ldsB[3][8192];
  const int K = FIN;
  const int NT = K / 32;  // 24 K-steps

  int t = threadIdx.x;
  int id = blockIdx.x;
  int xcd = id & 7, sq = id >> 3;
  int bm128 = xcd + 8 * (sq >> 2);

  if (bm128 < (M + 127) / 128) {  // block-uniform guard (barriers safe inside)
    int bm = bm128 * 128;
    int bn = (sq & 3) * 128;

    int lane = t & 63, w = t >> 6;
    int wm = w >> 1, wn = w & 1;
    int fr = lane & 15, fs = lane >> 4;

    f32x4 acc[4][4];
#pragma unroll
    for (int m = 0; m < 4; ++m)
#pragma unroll
      for (int n = 0; n < 4; ++n) acc[m][n] = (f32x4){0.f, 0.f, 0.f, 0.f};

    // fragment read offsets — verified zero-conflict geometry (R14)
    int aofE[4], aofO[4], boff[4];
#pragma unroll
    for (int m = 0; m < 4; ++m) {
      int r = wm * 64 + m * 16 + fr;
      aofE[m] = swz(r, fs);           // k [8fs, 8fs+4)   (even quad)
      aofO[m] = 8192 + swz(r, fs);    // k [8fs+4, 8fs+8) (odd quad)
    }
#pragma unroll
    for (int n = 0; n < 4; ++n) boff[n] = swz(wn * 64 + n * 16 + fr, fs);

    // staging: thread t -> row r0 = t>>2, phys slot t&3; logical quad l0
    int r0 = t >> 2;
    int l0 = (t & 3) ^ ((r0 >> 1) & 3);
    const float* srcA0 = A + (size_t)min(bm + r0, M - 1) * K + 8 * l0;     // even
    const float* srcA1 = A + (size_t)min(bm + 64 + r0, M - 1) * K + 8 * l0;
    const ushort_t* srcB0 = Bc + (size_t)(bn + r0) * K + l0 * 8;           // 8 bf16
    const ushort_t* srcB1 = Bc + (size_t)(bn + 64 + r0) * K + l0 * 8;

    // 6 glds per stage (4 A + 2 B); vmcnt counts these per-thread, in order.
#define STAGE(bi, k0) {                                                        \
    GLDS16(srcA0 + (k0),     ldsA[bi] + w * 1024);            /* E rows 0-63 */\
    GLDS16(srcA1 + (k0),     ldsA[bi] + 4096 + w * 1024);     /* E rows 64+  */\
    GLDS16(srcA0 + (k0) + 4, ldsA[bi] + 8192 + w * 1024);     /* O rows 0-63 */\
    GLDS16(srcA1 + (k0) + 4, ldsA[bi] + 12288 + w * 1024);    /* O rows 64+  */\
    GLDS16(srcB0 + (k0),     ldsB[bi] + w * 1024);                             \
    GLDS16(srcB1 + (k0),     ldsB[bi] + 4096 + w * 1024); }

    // prologue: two stages in flight (12 outstanding loads per thread);
    // kernel starts with vmcnt = 0 (no preamble VMEM), counting is exact.
    STAGE(0, 0);
    STAGE(1, 32);

    int cur = 0;
    for (int s = 0; s < NT; ++s) {
      // wait ONLY for the oldest stage (buf[cur]); newest stays in flight.
      if (s < NT - 1) {
        asm volatile("s_waitcnt vmcnt(6)" ::: "memory");
      } else {
        asm volatile("s_waitcnt vmcnt(0)" ::: "memory");
      }
      __builtin_amdgcn_sched_barrier(0);
      __builtin_amdgcn_s_barrier();  // all waves did their vmcnt -> buf ready
      bf16x8 af[4], bfr[4];
#pragma unroll
      for (int m = 0; m < 4; ++m) {
        f32x4 e4 = *(const f32x4*)(ldsA[cur] + aofE[m]);
        f32x4 o4 = *(const f32x4*)(ldsA[cur] + aofO[m]);
        uint4 au;
        au.x = pk2(e4[0], e4[1]); au.y = pk2(e4[2], e4[3]);
        au.z = pk2(o4[0], o4[1]); au.w = pk2(o4[2], o4[3]);
        af[m] = *(bf16x8*)&au;
      }
#pragma unroll
      for (int n = 0; n < 4; ++n) bfr[n] = *(const bf16x8*)(ldsB[cur] + boff[n]);
#pragma unroll
      for (int m = 0; m < 4; ++m)
#pragma unroll
        for (int n = 0; n < 4; ++n)
          acc[m][n] = __builtin_amdgcn_mfma_f32_16x16x32_bf16(af[m], bfr[n],
                                                              acc[m][n], 0, 0, 0);
      // stage buf[(s+2)%3] = buf[(s-1)%3]: last read in step s-1, which every
      // wave finished before barrier(s) -> safe to overwrite.
      if (s + 2 < NT) {
        int nb = cur + 2; if (nb >= 3) nb -= 3;
        STAGE(nb, (s + 2) * 32);
      }
      ++cur; if (cur == 3) cur = 0;
    }
#undef STAGE

    // epilogue: C/D layout col = lane&15, row = (lane>>4)*4 + reg [m89-verified]
#pragma unroll
    for (int m = 0; m < 4; ++m) {
      int rbase = bm + wm * 64 + m * 16 + fs * 4;
#pragma unroll
      for (int r4 = 0; r4 < 4; ++r4) {
        int row = rbase + r4;
        if (row < M) {
          ushort_t* crow = C + (size_t)row * 512 + bn + wn * 64 + fr;
#pragma unroll
          for (int n = 0; n < 4; ++n) crow[n * 16] = bf1(acc[m][n][r4]);
        }
      }
    }
  }

  // ---- edge-fill postamble (all blocks; overlaps other blocks' compute) ----
  {
    const int EPB = (NE + 1567) / 1568;  // 511 edges/block
    int e0 = id * EPB;
    int e1 = min(e0 + EPB, NE);
    for (int e = e0 + t; e < e1; e += 256) {
      int src = ei[e];
      int dst = ei[NE + e];
      int ty = et[e];
      unsigned pos = atomicAdd(&cursor[dst], 1u);
      if (pos < CAP)
        epw[(size_t)dst * CAP + pos] =
            make_uint2((uint32_t)src | ((uint32_t)ty << 16), 0u);
    }
  }
}

// ---------------- aggregation / epilogues ----------------

// one wave per dst node over hxb[NN][512] bf16 (cols 0..255 = hx, 256..511 = xr);
// INLINE NORM: lane l owns edge l, computes its (dst,t) count wave-uniformly,
// broadcasts ic via shfl in the main loop, writes ep[l].y for gather2.
// unroll-by-8 gather. Writes h1 (bf16) over own row's xr half.
__global__ __launch_bounds__(256) void gather1_k(const unsigned* __restrict__ cursor,
                                                 uint2* __restrict__ epw,
                                                 const float* __restrict__ comp1,
                                                 ushort_t* __restrict__ hxb,
                                                 const float* __restrict__ bias1,
                                                 uint32_t ka, uint32_t kb) {
  __shared__ float cs[NR];
  if (threadIdx.x < NR) cs[threadIdx.x] = comp1[threadIdx.x];
  __syncthreads();
  int node = blockIdx.x * 4 + (threadIdx.x >> 6);
  int lane = threadIdx.x & 63;
  if (node >= NN) return;
  int d = min((int)cursor[node], CAP);
  uint2* ep = epw + (size_t)node * CAP;
  // inline per-(dst,t) mean norm
  uint32_t myx = (lane < d) ? ep[lane].x : 0u;
  uint32_t mt = myx >> 16;
  int c = 0;
  for (int i = 0; i < d; ++i) c += ((ep[i].x >> 16) == mt) ? 1 : 0;
  float ic = 1.0f / (float)c;
  if (lane < d) ep[lane].y = __float_as_uint(ic);  // consumed by gather2
  float aA0 = 0.f, aA1 = 0.f, aA2 = 0.f, aA3 = 0.f;
  float aB0 = 0.f, aB1 = 0.f, aB2 = 0.f, aB3 = 0.f;
  int j = 0;
  for (; j + 8 <= d; j += 8) {
    uint32_t ex[8];
    uint2 u[8];
#pragma unroll
    for (int q = 0; q < 8; ++q) ex[q] = ep[j + q].x;
#pragma unroll
    for (int q = 0; q < 8; ++q)
      u[q] = *(const uint2*)(hxb + (size_t)(ex[q] & 0xFFFFu) * 512 + lane * 4);
#pragma unroll
    for (int q = 0; q < 8; ++q) {
      float w_ = cs[ex[q] >> 16] * __shfl(ic, j + q, 64);
      if (q & 1) {
        aB0 += w_ * ulo(u[q].x); aB1 += w_ * uhi(u[q].x);
        aB2 += w_ * ulo(u[q].y); aB3 += w_ * uhi(u[q].y);
      } else {
        aA0 += w_ * ulo(u[q].x); aA1 += w_ * uhi(u[q].x);
        aA2 += w_ * ulo(u[q].y); aA3 += w_ * uhi(u[q].y);
      }
    }
  }
  for (; j < d; ++j) {
    uint32_t ex = ep[j].x;
    uint2 u0 = *(const uint2*)(hxb + (size_t)(ex & 0xFFFFu) * 512 + lane * 4);
    float w0 = cs[ex >> 16] * __shfl(ic, j, 64);
    aA0 += w0 * ulo(u0.x); aA1 += w0 * uhi(u0.x);
    aA2 += w0 * ulo(u0.y); aA3 += w0 * uhi(u0.y);
  }
  float s0 = aA0 + aB0, s1 = aA1 + aB1, s2 = aA2 + aB2, s3 = aA3 + aB3;
  ushort_t* xrow = hxb + (size_t)node * 512 + 256 + lane * 4;
  uint2 xu = *(const uint2*)xrow;
  float4 b = *(const float4*)(bias1 + lane * 4);
  uint32_t base = (uint32_t)(node * HD + lane * 4);
  float ox = drelu(s0 + ulo(xu.x) + b.x, ka, kb, base + 0);
  float oy = drelu(s1 + uhi(xu.x) + b.y, ka, kb, base + 1);
  float oz = drelu(s2 + ulo(xu.y) + b.z, ka, kb, base + 2);
  float ow = drelu(s3 + uhi(xu.y) + b.w, ka, kb, base + 3);
  *(uint2*)xrow = make_uint2(pk2(ox, oy), pk2(oz, ow));
}

// layer-2 projections, thread per node: hxr2[n][0..8] = h1@basis2 ; [10..18] = h1@root2
// W reads are wave-uniform (broadcast, conflict-free). hxr2 row stride 20 floats.
__global__ __launch_bounds__(256) void gemm2_k(const ushort_t* __restrict__ hxb,
                                               const float* __restrict__ basis2,
                                               const float* __restrict__ root2,
                                               float* __restrict__ hxr2) {
  __shared__ float W[256][20];  // padded stride
  int tid = threadIdx.x;
  for (int p = tid; p < 256 * 18; p += 256) {
    int k = p / 18, c = p % 18;
    W[k][c] = (c < 9) ? basis2[k * 9 + c] : root2[k * 9 + (c - 9)];
  }
  __syncthreads();
  int n = blockIdx.x * 256 + tid;
  if (n >= NN) return;
  const ushort_t* hp = hxb + (size_t)n * 512 + 256;
  float acc[18];
#pragma unroll
  for (int c = 0; c < 18; ++c) acc[c] = 0.f;
  for (int k0 = 0; k0 < 256; k0 += 8) {
    uint4 u = *(const uint4*)(hp + k0);
    float f[8];
    f[0] = ulo(u.x); f[1] = uhi(u.x); f[2] = ulo(u.y); f[3] = uhi(u.y);
    f[4] = ulo(u.z); f[5] = uhi(u.z); f[6] = ulo(u.w); f[7] = uhi(u.w);
#pragma unroll
    for (int q = 0; q < 8; ++q)
#pragma unroll
      for (int c = 0; c < 18; ++c) acc[c] += f[q] * W[k0 + q][c];
  }
  float* op = hxr2 + (size_t)n * 20;
#pragma unroll
  for (int c = 0; c < 9; ++c) op[c] = acc[c];
#pragma unroll
  for (int c = 0; c < 9; ++c) op[10 + c] = acc[9 + c];
}

// one thread per dst node, unroll-by-4: out = relu(dropout(agg + xr2 + b2))
__global__ __launch_bounds__(256) void gather2_k(const unsigned* __restrict__ cursor,
                                                 const uint2* __restrict__ epw,
                                                 const float* __restrict__ comp2,
                                                 const float* __restrict__ hxr2,
                                                 const float* __restrict__ bias2,
                                                 float* __restrict__ out,
                                                 uint32_t ka, uint32_t kb) {
  __shared__ float cs[NR];
  if (threadIdx.x < NR) cs[threadIdx.x] = comp2[threadIdx.x];
  __syncthreads();
  int n = blockIdx.x * 256 + threadIdx.x;
  if (n >= NN) return;
  int d = min((int)cursor[n], CAP);
  const uint2* ep = epw + (size_t)n * CAP;
  float a[9];
#pragma unroll
  for (int c = 0; c < 9; ++c) a[c] = 0.f;
  int j = 0;
  for (; j + 4 <= d; j += 4) {
    uint2 e[4];
    float4 pa[4], pb[4];
    float pe[4];
#pragma unroll
    for (int q = 0; q < 4; ++q) e[q] = ep[j + q];
#pragma unroll
    for (int q = 0; q < 4; ++q) {
      const float* hp = hxr2 + (size_t)(e[q].x & 0xFFFFu) * 20;
      pa[q] = *(const float4*)hp;
      pb[q] = *(const float4*)(hp + 4);
      pe[q] = hp[8];
    }
#pragma unroll
    for (int q = 0; q < 4; ++q) {
      float w_ = cs[e[q].x >> 16] * __uint_as_float(e[q].y);
      a[0] += w_ * pa[q].x; a[1] += w_ * pa[q].y;
      a[2] += w_ * pa[q].z; a[3] += w_ * pa[q].w;
      a[4] += w_ * pb[q].x; a[5] += w_ * pb[q].y;
      a[6] += w_ * pb[q].z; a[7] += w_ * pb[q].w;
      a[8] += w_ * pe[q];
    }
  }
  for (; j < d; ++j) {
    uint2 e0 = ep[j];
    const float* hp = hxr2 + (size_t)(e0.x & 0xFFFFu) * 20;
    float4 p0a = *(const float4*)hp, p0b = *(const float4*)(hp + 4);
    float p0e = hp[8];
    float w0 = cs[e0.x >> 16] * __uint_as_float(e0.y);
    a[0] += w0 * p0a.x; a[1] += w0 * p0a.y; a[2] += w0 * p0a.z; a[3] += w0 * p0a.w;
    a[4] += w0 * p0b.x; a[5] += w0 * p0b.y; a[6] += w0 * p0b.z; a[7] += w0 * p0b.w;
    a[8] += w0 * p0e;
  }
  const float* xp = hxr2 + (size_t)n * 20 + 10;
#pragma unroll
  for (int c = 0; c < 9; ++c) {
    float v = a[c] + xp[c] + bias2[c];
    out[n * 9 + c] = drelu(v, ka, kb, (uint32_t)(n * 9 + c));
  }
}

// ---------------- launch ----------------
extern "C" void kernel_launch(void* const* d_in, const int* in_sizes, int n_in,
                              void* d_out, int out_size, void* d_ws, size_t ws_size,
                              hipStream_t stream) {
  (void)in_sizes; (void)n_in; (void)out_size; (void)ws_size;
  const float* x      = (const float*)d_in[0];
  const int*   ei     = (const int*)d_in[1];
  const int*   et     = (const int*)d_in[2];
  const float* basis1 = (const float*)d_in[4];
  const float* comp1  = (const float*)d_in[5];
  const float* root1  = (const float*)d_in[6];
  const float* bias1  = (const float*)d_in[7];
  const float* basis2 = (const float*)d_in[8];
  const float* comp2  = (const float*)d_in[9];
  const float* root2  = (const float*)d_in[10];
  const float* bias2  = (const float*)d_in[11];
  float* out = (float*)d_out;

  // workspace layout (bytes); total ~81.8 MB (no xb — GEMM reads x directly)
  char* ws = (char*)d_ws;
  ushort_t* Bcat   = (ushort_t*)(ws);                        //     786,432
  uint2* epw       = (uint2*)(ws + 786432);                  //  25,600,000
  unsigned* cursor = (unsigned*)(ws + 26386432);             //     200,128
  ushort_t* hxb    = (ushort_t*)(ws + 26586560);             //  51,200,000
  float* hxr2      = (float*)(ws + 77786560);                //   4,000,128

  // k1, k2 = jax.random.split(jax.random.key(42)), partitionable scheme
  uint32_t k1a, k1b, k2a, k2b;
  tf2x32(0u, 42u, 0u, 0u, k1a, k1b);
  tf2x32(0u, 42u, 0u, 1u, k2a, k2b);

  hipMemsetAsync(cursor, 0, 200128, stream);

  bcat_k<<<(512 * FIN + 255) / 256, 256, 0, stream>>>(basis1, root1, Bcat);

  // 1568 = 8 XCDs x 196 seq slots; 4 blocks do only the edge-fill postamble
  mfma_gemm_k<<<1568, 256, 0, stream>>>(x, Bcat, hxb, NN, ei, et, cursor, epw);

  gather1_k<<<(NN + 3) / 4, 256, 0, stream>>>(cursor, epw, comp1, hxb, bias1,
                                              k1a, k1b);

  gemm2_k<<<(NN + 255) / 256, 256, 0, stream>>>(hxb, basis2, root2, hxr2);

  gather2_k<<<(NN + 255) / 256, 256, 0, stream>>>(cursor, epw, comp2, hxr2,
                                                  bias2, out, k2a, k2b);
}